// Round 4
// baseline (3685.578 us; speedup 1.0000x reference)
//
#include <hip/hip_runtime.h>
#include <hip/hip_bf16.h>

// MoE: T=2048 tokens, H=2048 hidden, I=5632 intermediate, E=8 experts, top-2 renormalized.
// route -> per-expert token lists -> cvt x to bf16 (scratch = d_out) -> grouped GEMM1
// (x@w1^T fused SwiGLU, bf16 h to ws) -> memset out -> grouped GEMM2 (h@w2^T, *w, atomicAdd).
// GEMMs use a 2-deep register-staged pipeline with raw s_barrier (no vmcnt drain).

#define TT 2048
#define HH 2048
#define II 5632
#define NE 8

using f32x4  = __attribute__((ext_vector_type(4))) float;
using bf16x8 = __attribute__((ext_vector_type(8))) short;

__device__ __forceinline__ uint32_t bfbits(float f) {
    __hip_bfloat16 h = __float2bfloat16(f);
    unsigned short u;
    __builtin_memcpy(&u, &h, 2);
    return (uint32_t)u;
}
__device__ __forceinline__ uint32_t pk2(float a, float b) {
    return bfbits(a) | (bfbits(b) << 16);
}
__device__ __forceinline__ uint4 pk8(const float4& a, const float4& b) {
    uint4 r;
    r.x = pk2(a.x, a.y); r.y = pk2(a.z, a.w);
    r.z = pk2(b.x, b.y); r.w = pk2(b.z, b.w);
    return r;
}

// lgkm drain (my ds ops done) -> raw barrier (everyone's done), sched-pinned both sides
#define FENCE() do { \
    asm volatile("s_waitcnt lgkmcnt(0)" ::: "memory"); \
    __builtin_amdgcn_sched_barrier(0); \
    __builtin_amdgcn_s_barrier(); \
    __builtin_amdgcn_sched_barrier(0); \
} while (0)

// ---------------- x -> bf16 ----------------
__global__ void cvt_x(const float* __restrict__ x, __hip_bfloat16* __restrict__ xb) {
    const int i = (blockIdx.x * 256 + threadIdx.x) * 8;
    float4 a = *(const float4*)(x + i);
    float4 b = *(const float4*)(x + i + 4);
    *(uint4*)(xb + i) = pk8(a, b);
}

// ---------------- routing ----------------
__global__ void route_topk(const float* __restrict__ gating,
                           int* __restrict__ tk_idx, float* __restrict__ tk_w) {
    int t = blockIdx.x * 256 + threadIdx.x;
    if (t >= TT) return;
    float g[NE];
#pragma unroll
    for (int e = 0; e < NE; e++) g[e] = gating[t * NE + e];
    int i0 = 0; float b0 = g[0];
#pragma unroll
    for (int e = 1; e < NE; e++) if (g[e] > b0) { b0 = g[e]; i0 = e; }
    int i1 = (i0 == 0) ? 1 : 0; float b1 = g[i1];
#pragma unroll
    for (int e = 0; e < NE; e++) if (e != i0 && g[e] > b1) { b1 = g[e]; i1 = e; }
    float ex = expf(b1 - b0);
    float w0 = 1.f / (1.f + ex);
    float w1 = ex / (1.f + ex);
    tk_idx[2 * t] = i0; tk_idx[2 * t + 1] = i1;
    tk_w[2 * t] = w0;  tk_w[2 * t + 1] = w1;
}

// one block per expert: deterministic compaction via block scan (token order preserved)
__global__ void build_lists(const int* __restrict__ tk_idx, const float* __restrict__ tk_w,
                            int* __restrict__ list_tok, float* __restrict__ list_w,
                            int* __restrict__ counts) {
    const int e = blockIdx.x;
    const int tid = threadIdx.x;
    int flag[8]; float wt[8];
    int cnt = 0;
#pragma unroll
    for (int j = 0; j < 8; j++) {
        int t = tid * 8 + j;
        int f = -1;
        if (tk_idx[2 * t] == e) f = 0;
        else if (tk_idx[2 * t + 1] == e) f = 1;
        flag[j] = f;
        wt[j] = (f >= 0) ? tk_w[2 * t + f] : 0.f;
        cnt += (f >= 0) ? 1 : 0;
    }
    __shared__ int s[256];
    s[tid] = cnt;
    __syncthreads();
    for (int d = 1; d < 256; d <<= 1) {
        int v = (tid >= d) ? s[tid - d] : 0;
        __syncthreads();
        s[tid] += v;
        __syncthreads();
    }
    int pos = s[tid] - cnt;
#pragma unroll
    for (int j = 0; j < 8; j++) {
        if (flag[j] >= 0) {
            list_tok[e * TT + pos] = tid * 8 + j;
            list_w[e * TT + pos] = wt[j];
            pos++;
        }
    }
    if (tid == 255) counts[e] = s[255];
}

// ---------------- GEMM1: h = SwiGLU(Xe @ w1[e]^T), tile 128(M) x 64(N of I), BK=32 ----------------
__global__ __launch_bounds__(256, 4) void gemm1_swiglu(
    const __hip_bfloat16* __restrict__ xb, const float* __restrict__ w1,
    const int* __restrict__ list_tok, const int* __restrict__ counts,
    __hip_bfloat16* __restrict__ hbuf) {
    const int e = blockIdx.y >> 4;
    const int mt = blockIdx.y & 15;
    const int cnt = counts[e];
    const int row0 = mt * 128;
    if (row0 >= cnt) return;
    int off = 0;
#pragma unroll
    for (int i = 0; i < NE; i++) if (i < e) off += counts[i];
    const int valid = min(128, cnt - row0);
    const int n0 = blockIdx.x * 64;
    const int tid = threadIdx.x;

    __shared__ uint4 As[2][512];   // 128 rows x 32 bf16 (4 x 16B slots/row), swizzled
    __shared__ uint4 Bg[2][256];   // 64 x 32
    __shared__ uint4 Bu[2][256];

    const int ar0 = tid >> 2, au = tid & 3;
    const int ar1 = ar0 + 64;
    const int tokA0 = list_tok[e * TT + row0 + min(ar0, valid - 1)];
    const int tokA1 = list_tok[e * TT + row0 + min(ar1, valid - 1)];
    const __hip_bfloat16* aS0 = xb + (size_t)tokA0 * HH + au * 8;
    const __hip_bfloat16* aS1 = xb + (size_t)tokA1 * HH + au * 8;
    const float* gS = w1 + (size_t)e * (2 * II) * HH + (size_t)(n0 + ar0) * HH + au * 8;
    const float* uS = gS + (size_t)II * HH;
    const int awi0 = ar0 * 4 + (au ^ ((ar0 >> 1) & 3));
    const int awi1 = ar1 * 4 + (au ^ ((ar1 >> 1) & 3));
    const int bwi  = ar0 * 4 + (au ^ ((ar0 >> 1) & 3));

    struct R1 { uint4 a0, a1; float4 g0, g1, u0, u1; };
    R1 ra, rb;
    auto LD = [&](R1& r, int kt) {
        const int k = kt * 32;
        r.g0 = *(const float4*)(gS + k); r.g1 = *(const float4*)(gS + k + 4);
        r.u0 = *(const float4*)(uS + k); r.u1 = *(const float4*)(uS + k + 4);
        r.a0 = *(const uint4*)(aS0 + k);
        r.a1 = *(const uint4*)(aS1 + k);
    };
    auto ST = [&](const R1& r, int b) {
        As[b][awi0] = r.a0;
        As[b][awi1] = r.a1;
        Bg[b][bwi]  = pk8(r.g0, r.g1);
        Bu[b][bwi]  = pk8(r.u0, r.u1);
    };

    // fragment indices: wave grid 2x2, wave tile 64(M) x 32(N)
    const int lane = tid & 63;
    const int wv = tid >> 6;
    const int wm = wv >> 1, wn = wv & 1;
    const int l15 = lane & 15, ks = lane >> 4;
    int aidx[4], bidx[2];
#pragma unroll
    for (int m = 0; m < 4; m++) { int r = wm * 64 + m * 16 + l15; aidx[m] = r * 4 + (ks ^ ((r >> 1) & 3)); }
#pragma unroll
    for (int n = 0; n < 2; n++) { int c = wn * 32 + n * 16 + l15; bidx[n] = c * 4 + (ks ^ ((c >> 1) & 3)); }

    f32x4 accg[4][2], accu[4][2];
#pragma unroll
    for (int m = 0; m < 4; m++)
#pragma unroll
        for (int n = 0; n < 2; n++) { accg[m][n] = 0; accu[m][n] = 0; }

    auto RD = [&](int b, bf16x8* af, bf16x8* gf, bf16x8* uf) {
#pragma unroll
        for (int m = 0; m < 4; m++) { uint4 t = As[b][aidx[m]]; af[m] = __builtin_bit_cast(bf16x8, t); }
#pragma unroll
        for (int n = 0; n < 2; n++) {
            uint4 t = Bg[b][bidx[n]]; gf[n] = __builtin_bit_cast(bf16x8, t);
            uint4 t2 = Bu[b][bidx[n]]; uf[n] = __builtin_bit_cast(bf16x8, t2);
        }
    };
    auto MM = [&](bf16x8* af, bf16x8* gf, bf16x8* uf) {
#pragma unroll
        for (int m = 0; m < 4; m++)
#pragma unroll
            for (int n = 0; n < 2; n++) {
                accg[m][n] = __builtin_amdgcn_mfma_f32_16x16x32_bf16(af[m], gf[n], accg[m][n], 0, 0, 0);
                accu[m][n] = __builtin_amdgcn_mfma_f32_16x16x32_bf16(af[m], uf[n], accu[m][n], 0, 0, 0);
            }
    };

    const int KT = HH / 32;  // 64 (even)
    LD(ra, 0); LD(rb, 1);
    ST(ra, 0);
    FENCE();
    for (int kt = 0; kt < KT; kt += 2) {
        {   // even: compute LDS[0] (tile kt); store tile kt+1 -> LDS[1]; load tile kt+2 -> ra
            bf16x8 af[4], gf[2], uf[2];
            RD(0, af, gf, uf);
            if (kt + 2 < KT) LD(ra, kt + 2);
            ST(rb, 1);
            FENCE();
            MM(af, gf, uf);
        }
        {   // odd: compute LDS[1] (tile kt+1); store tile kt+2 -> LDS[0]; load tile kt+3 -> rb
            bf16x8 af[4], gf[2], uf[2];
            RD(1, af, gf, uf);
            if (kt + 3 < KT) LD(rb, kt + 3);
            if (kt + 2 < KT) ST(ra, 0);
            FENCE();
            MM(af, gf, uf);
        }
    }

    // epilogue: h = silu(g)*u -> bf16
#pragma unroll
    for (int m = 0; m < 4; m++) {
#pragma unroll
        for (int r = 0; r < 4; r++) {
            const int lr = wm * 64 + m * 16 + ks * 4 + r;   // C row = (lane>>4)*4 + reg
            if (lr < valid) {
                __hip_bfloat16* hrow = hbuf + (size_t)(off + row0 + lr) * II;
#pragma unroll
                for (int n = 0; n < 2; n++) {
                    const int col = n0 + wn * 32 + n * 16 + l15;   // C col = lane&15
                    float g = accg[m][n][r], u = accu[m][n][r];
                    float h = g / (1.f + __expf(-g)) * u;
                    hrow[col] = __float2bfloat16(h);
                }
            }
        }
    }
}

// ---------------- GEMM2: out += (h @ w2[e]^T) * route_w, tile 128x128, BK=32 ----------------
__global__ __launch_bounds__(256, 3) void gemm2_scatter(
    const __hip_bfloat16* __restrict__ hbuf, const float* __restrict__ w2,
    const int* __restrict__ list_tok, const float* __restrict__ list_w,
    const int* __restrict__ counts, float* __restrict__ out) {
    const int e = blockIdx.y >> 4;
    const int mt = blockIdx.y & 15;
    const int cnt = counts[e];
    const int row0 = mt * 128;
    if (row0 >= cnt) return;
    int off = 0;
#pragma unroll
    for (int i = 0; i < NE; i++) if (i < e) off += counts[i];
    const int valid = min(128, cnt - row0);
    const int n0 = blockIdx.x * 128;
    const int tid = threadIdx.x;

    __shared__ uint4 As[2][512];
    __shared__ uint4 Bs[2][512];

    const int ar0 = tid >> 2, au = tid & 3;
    const int ar1 = ar0 + 64;
    const size_t hr0 = (size_t)(off + row0 + min(ar0, valid - 1)) * II + au * 8;
    const size_t hr1 = (size_t)(off + row0 + min(ar1, valid - 1)) * II + au * 8;
    const float* bS0 = w2 + (size_t)e * HH * II + (size_t)(n0 + ar0) * II + au * 8;
    const float* bS1 = bS0 + (size_t)64 * II;
    const int awi0 = ar0 * 4 + (au ^ ((ar0 >> 1) & 3));
    const int awi1 = ar1 * 4 + (au ^ ((ar1 >> 1) & 3));

    struct R2 { uint4 a0, a1; float4 b0, b1, b2, b3; };
    R2 ra, rb;
    auto LD = [&](R2& r, int kt) {
        const int k = kt * 32;
        r.b0 = *(const float4*)(bS0 + k); r.b1 = *(const float4*)(bS0 + k + 4);
        r.b2 = *(const float4*)(bS1 + k); r.b3 = *(const float4*)(bS1 + k + 4);
        r.a0 = *(const uint4*)(hbuf + hr0 + k);
        r.a1 = *(const uint4*)(hbuf + hr1 + k);
    };
    auto ST = [&](const R2& r, int b) {
        As[b][awi0] = r.a0;
        As[b][awi1] = r.a1;
        Bs[b][awi0] = pk8(r.b0, r.b1);
        Bs[b][awi1] = pk8(r.b2, r.b3);
    };

    // wave tile 64x64
    const int lane = tid & 63;
    const int wv = tid >> 6;
    const int wm = wv >> 1, wn = wv & 1;
    const int l15 = lane & 15, ks = lane >> 4;
    int aidx[4], bidx[4];
#pragma unroll
    for (int m = 0; m < 4; m++) { int r = wm * 64 + m * 16 + l15; aidx[m] = r * 4 + (ks ^ ((r >> 1) & 3)); }
#pragma unroll
    for (int n = 0; n < 4; n++) { int c = wn * 64 + n * 16 + l15; bidx[n] = c * 4 + (ks ^ ((c >> 1) & 3)); }

    f32x4 acc[4][4];
#pragma unroll
    for (int m = 0; m < 4; m++)
#pragma unroll
        for (int n = 0; n < 4; n++) acc[m][n] = 0;

    auto RD = [&](int b, bf16x8* af, bf16x8* bf) {
#pragma unroll
        for (int m = 0; m < 4; m++) { uint4 t = As[b][aidx[m]]; af[m] = __builtin_bit_cast(bf16x8, t); }
#pragma unroll
        for (int n = 0; n < 4; n++) { uint4 t = Bs[b][bidx[n]]; bf[n] = __builtin_bit_cast(bf16x8, t); }
    };
    auto MM = [&](bf16x8* af, bf16x8* bf) {
#pragma unroll
        for (int m = 0; m < 4; m++)
#pragma unroll
            for (int n = 0; n < 4; n++)
                acc[m][n] = __builtin_amdgcn_mfma_f32_16x16x32_bf16(af[m], bf[n], acc[m][n], 0, 0, 0);
    };

    const int KT = II / 32;  // 176 (even)
    LD(ra, 0); LD(rb, 1);
    ST(ra, 0);
    FENCE();
    for (int kt = 0; kt < KT; kt += 2) {
        {
            bf16x8 af[4], bf[4];
            RD(0, af, bf);
            if (kt + 2 < KT) LD(ra, kt + 2);
            ST(rb, 1);
            FENCE();
            MM(af, bf);
        }
        {
            bf16x8 af[4], bf[4];
            RD(1, af, bf);
            if (kt + 3 < KT) LD(rb, kt + 3);
            if (kt + 2 < KT) ST(ra, 0);
            FENCE();
            MM(af, bf);
        }
    }

    // epilogue: scale by routing weight, scatter-add to out
#pragma unroll
    for (int m = 0; m < 4; m++) {
#pragma unroll
        for (int r = 0; r < 4; r++) {
            const int lr = wm * 64 + m * 16 + ks * 4 + r;
            if (lr < valid) {
                const int tok = list_tok[e * TT + row0 + lr];
                const float wt = list_w[e * TT + row0 + lr];
                float* orow = out + (size_t)tok * HH;
#pragma unroll
                for (int n = 0; n < 4; n++) {
                    const int col = n0 + wn * 64 + n * 16 + l15;
                    atomicAdd(orow + col, acc[m][n][r] * wt);
                }
            }
        }
    }
}

extern "C" void kernel_launch(void* const* d_in, const int* in_sizes, int n_in,
                              void* d_out, int out_size, void* d_ws, size_t ws_size,
                              hipStream_t stream) {
    const float* x      = (const float*)d_in[0];
    const float* gating = (const float*)d_in[1];
    const float* w1     = (const float*)d_in[2];
    const float* w2     = (const float*)d_in[3];
    float* out = (float*)d_out;
    char* ws = (char*)d_ws;

    int*   list_tok = (int*)(ws + 0);              // 64 KB
    float* list_w   = (float*)(ws + (64 << 10));   // 64 KB
    int*   counts   = (int*)(ws + (128 << 10));    // 32 B
    int*   tk_idx   = (int*)(ws + (132 << 10));    // 16 KB
    float* tk_w     = (float*)(ws + (148 << 10));  // 16 KB
    __hip_bfloat16* hbuf = (__hip_bfloat16*)(ws + (1 << 20));  // 4096 x 5632 bf16 = 46.1 MB

    // xb (bf16 x, 8.4 MB) lives in d_out until gemm1 is done; memset before gemm2.
    __hip_bfloat16* xb = (__hip_bfloat16*)d_out;

    route_topk<<<TT / 256, 256, 0, stream>>>(gating, tk_idx, tk_w);
    build_lists<<<NE, 256, 0, stream>>>(tk_idx, tk_w, list_tok, list_w, counts);
    cvt_x<<<TT * HH / (256 * 8), 256, 0, stream>>>(x, xb);
    gemm1_swiglu<<<dim3(II / 64, NE * 16), 256, 0, stream>>>(xb, w1, list_tok, counts, hbuf);
    (void)hipMemsetAsync(d_out, 0, (size_t)TT * HH * sizeof(float), stream);
    gemm2_scatter<<<dim3(HH / 128, NE * 16), 256, 0, stream>>>(hbuf, w2, list_tok, list_w, counts, out);
}

// Round 5
// 1531.851 us; speedup vs baseline: 2.4060x; 2.4060x over previous
//
#include <hip/hip_runtime.h>
#include <hip/hip_bf16.h>

// MoE: T=2048 tokens, H=2048 hidden, I=5632 intermediate, E=8 experts, top-2 renormalized.
// route -> per-expert token lists -> cvt x to bf16 (scratch = d_out) -> grouped GEMM1
// (x@w1^T fused SwiGLU, bf16 h to ws) -> memset out -> grouped GEMM2 (h@w2^T, *w, atomicAdd).
// GEMMs use a 2-deep register-staged pipeline with raw s_barrier (no vmcnt drain).
// NOTE: launch_bounds must stay (256,2) — tighter caps spill the pipeline registers
// to scratch (R4: WRITE_SIZE 45MB -> 8.3GB, 7x slowdown).

#define TT 2048
#define HH 2048
#define II 5632
#define NE 8

using f32x4  = __attribute__((ext_vector_type(4))) float;
using bf16x8 = __attribute__((ext_vector_type(8))) short;

__device__ __forceinline__ uint32_t bfbits(float f) {
    __hip_bfloat16 h = __float2bfloat16(f);
    unsigned short u;
    __builtin_memcpy(&u, &h, 2);
    return (uint32_t)u;
}
__device__ __forceinline__ uint32_t pk2(float a, float b) {
    return bfbits(a) | (bfbits(b) << 16);
}
__device__ __forceinline__ uint4 pk8(const float4& a, const float4& b) {
    uint4 r;
    r.x = pk2(a.x, a.y); r.y = pk2(a.z, a.w);
    r.z = pk2(b.x, b.y); r.w = pk2(b.z, b.w);
    return r;
}

// lgkm drain (my ds ops done) -> raw barrier (everyone's done), sched-pinned both sides
#define FENCE() do { \
    asm volatile("s_waitcnt lgkmcnt(0)" ::: "memory"); \
    __builtin_amdgcn_sched_barrier(0); \
    __builtin_amdgcn_s_barrier(); \
    __builtin_amdgcn_sched_barrier(0); \
} while (0)

// ---------------- x -> bf16 ----------------
__global__ void cvt_x(const float* __restrict__ x, __hip_bfloat16* __restrict__ xb) {
    const int i = (blockIdx.x * 256 + threadIdx.x) * 8;
    float4 a = *(const float4*)(x + i);
    float4 b = *(const float4*)(x + i + 4);
    *(uint4*)(xb + i) = pk8(a, b);
}

// ---------------- routing ----------------
__global__ void route_topk(const float* __restrict__ gating,
                           int* __restrict__ tk_idx, float* __restrict__ tk_w) {
    int t = blockIdx.x * 256 + threadIdx.x;
    if (t >= TT) return;
    float g[NE];
#pragma unroll
    for (int e = 0; e < NE; e++) g[e] = gating[t * NE + e];
    int i0 = 0; float b0 = g[0];
#pragma unroll
    for (int e = 1; e < NE; e++) if (g[e] > b0) { b0 = g[e]; i0 = e; }
    int i1 = (i0 == 0) ? 1 : 0; float b1 = g[i1];
#pragma unroll
    for (int e = 0; e < NE; e++) if (e != i0 && g[e] > b1) { b1 = g[e]; i1 = e; }
    float ex = expf(b1 - b0);
    float w0 = 1.f / (1.f + ex);
    float w1 = ex / (1.f + ex);
    tk_idx[2 * t] = i0; tk_idx[2 * t + 1] = i1;
    tk_w[2 * t] = w0;  tk_w[2 * t + 1] = w1;
}

// one block per expert: deterministic compaction via block scan (token order preserved)
__global__ void build_lists(const int* __restrict__ tk_idx, const float* __restrict__ tk_w,
                            int* __restrict__ list_tok, float* __restrict__ list_w,
                            int* __restrict__ counts) {
    const int e = blockIdx.x;
    const int tid = threadIdx.x;
    int flag[8]; float wt[8];
    int cnt = 0;
#pragma unroll
    for (int j = 0; j < 8; j++) {
        int t = tid * 8 + j;
        int f = -1;
        if (tk_idx[2 * t] == e) f = 0;
        else if (tk_idx[2 * t + 1] == e) f = 1;
        flag[j] = f;
        wt[j] = (f >= 0) ? tk_w[2 * t + f] : 0.f;
        cnt += (f >= 0) ? 1 : 0;
    }
    __shared__ int s[256];
    s[tid] = cnt;
    __syncthreads();
    for (int d = 1; d < 256; d <<= 1) {
        int v = (tid >= d) ? s[tid - d] : 0;
        __syncthreads();
        s[tid] += v;
        __syncthreads();
    }
    int pos = s[tid] - cnt;
#pragma unroll
    for (int j = 0; j < 8; j++) {
        if (flag[j] >= 0) {
            list_tok[e * TT + pos] = tid * 8 + j;
            list_w[e * TT + pos] = wt[j];
            pos++;
        }
    }
    if (tid == 255) counts[e] = s[255];
}

// ---------------- GEMM1: h = SwiGLU(Xe @ w1[e]^T), tile 128(M) x 64(N of I), BK=32 ----------------
__global__ __launch_bounds__(256, 2) void gemm1_swiglu(
    const __hip_bfloat16* __restrict__ xb, const float* __restrict__ w1,
    const int* __restrict__ list_tok, const int* __restrict__ counts,
    __hip_bfloat16* __restrict__ hbuf) {
    const int e = blockIdx.y >> 4;
    const int mt = blockIdx.y & 15;
    const int cnt = counts[e];
    const int row0 = mt * 128;
    if (row0 >= cnt) return;
    int off = 0;
#pragma unroll
    for (int i = 0; i < NE; i++) if (i < e) off += counts[i];
    const int valid = min(128, cnt - row0);
    const int n0 = blockIdx.x * 64;
    const int tid = threadIdx.x;

    __shared__ uint4 As[2][512];   // 128 rows x 32 bf16 (4 x 16B slots/row), swizzled
    __shared__ uint4 Bg[2][256];   // 64 x 32
    __shared__ uint4 Bu[2][256];

    const int ar0 = tid >> 2, au = tid & 3;
    const int ar1 = ar0 + 64;
    const int tokA0 = list_tok[e * TT + row0 + min(ar0, valid - 1)];
    const int tokA1 = list_tok[e * TT + row0 + min(ar1, valid - 1)];
    const __hip_bfloat16* aS0 = xb + (size_t)tokA0 * HH + au * 8;
    const __hip_bfloat16* aS1 = xb + (size_t)tokA1 * HH + au * 8;
    const float* gS = w1 + (size_t)e * (2 * II) * HH + (size_t)(n0 + ar0) * HH + au * 8;
    const float* uS = gS + (size_t)II * HH;
    const int awi0 = ar0 * 4 + (au ^ ((ar0 >> 1) & 3));
    const int awi1 = ar1 * 4 + (au ^ ((ar1 >> 1) & 3));
    const int bwi  = ar0 * 4 + (au ^ ((ar0 >> 1) & 3));

    struct R1 { uint4 a0, a1; float4 g0, g1, u0, u1; };
    R1 ra, rb;
    auto LD = [&](R1& r, int kt) {
        const int k = kt * 32;
        r.g0 = *(const float4*)(gS + k); r.g1 = *(const float4*)(gS + k + 4);
        r.u0 = *(const float4*)(uS + k); r.u1 = *(const float4*)(uS + k + 4);
        r.a0 = *(const uint4*)(aS0 + k);
        r.a1 = *(const uint4*)(aS1 + k);
    };
    auto ST = [&](const R1& r, int b) {
        As[b][awi0] = r.a0;
        As[b][awi1] = r.a1;
        Bg[b][bwi]  = pk8(r.g0, r.g1);
        Bu[b][bwi]  = pk8(r.u0, r.u1);
    };

    // fragment indices: wave grid 2x2, wave tile 64(M) x 32(N)
    const int lane = tid & 63;
    const int wv = tid >> 6;
    const int wm = wv >> 1, wn = wv & 1;
    const int l15 = lane & 15, ks = lane >> 4;
    int aidx[4], bidx[2];
#pragma unroll
    for (int m = 0; m < 4; m++) { int r = wm * 64 + m * 16 + l15; aidx[m] = r * 4 + (ks ^ ((r >> 1) & 3)); }
#pragma unroll
    for (int n = 0; n < 2; n++) { int c = wn * 32 + n * 16 + l15; bidx[n] = c * 4 + (ks ^ ((c >> 1) & 3)); }

    f32x4 accg[4][2], accu[4][2];
#pragma unroll
    for (int m = 0; m < 4; m++)
#pragma unroll
        for (int n = 0; n < 2; n++) { accg[m][n] = 0; accu[m][n] = 0; }

    auto RD = [&](int b, bf16x8* af, bf16x8* gf, bf16x8* uf) {
#pragma unroll
        for (int m = 0; m < 4; m++) { uint4 t = As[b][aidx[m]]; af[m] = __builtin_bit_cast(bf16x8, t); }
#pragma unroll
        for (int n = 0; n < 2; n++) {
            uint4 t = Bg[b][bidx[n]]; gf[n] = __builtin_bit_cast(bf16x8, t);
            uint4 t2 = Bu[b][bidx[n]]; uf[n] = __builtin_bit_cast(bf16x8, t2);
        }
    };
    auto MM = [&](bf16x8* af, bf16x8* gf, bf16x8* uf) {
#pragma unroll
        for (int m = 0; m < 4; m++)
#pragma unroll
            for (int n = 0; n < 2; n++) {
                accg[m][n] = __builtin_amdgcn_mfma_f32_16x16x32_bf16(af[m], gf[n], accg[m][n], 0, 0, 0);
                accu[m][n] = __builtin_amdgcn_mfma_f32_16x16x32_bf16(af[m], uf[n], accu[m][n], 0, 0, 0);
            }
    };

    const int KT = HH / 32;  // 64 (even)
    LD(ra, 0); LD(rb, 1);
    ST(ra, 0);
    FENCE();
    for (int kt = 0; kt < KT; kt += 2) {
        {   // even: compute LDS[0] (tile kt); store tile kt+1 -> LDS[1]; load tile kt+2 -> ra
            bf16x8 af[4], gf[2], uf[2];
            RD(0, af, gf, uf);
            if (kt + 2 < KT) LD(ra, kt + 2);
            ST(rb, 1);
            FENCE();
            MM(af, gf, uf);
        }
        {   // odd: compute LDS[1] (tile kt+1); store tile kt+2 -> LDS[0]; load tile kt+3 -> rb
            bf16x8 af[4], gf[2], uf[2];
            RD(1, af, gf, uf);
            if (kt + 3 < KT) LD(rb, kt + 3);
            if (kt + 2 < KT) ST(ra, 0);
            FENCE();
            MM(af, gf, uf);
        }
    }

    // epilogue: h = silu(g)*u -> bf16
#pragma unroll
    for (int m = 0; m < 4; m++) {
#pragma unroll
        for (int r = 0; r < 4; r++) {
            const int lr = wm * 64 + m * 16 + ks * 4 + r;   // C row = (lane>>4)*4 + reg
            if (lr < valid) {
                __hip_bfloat16* hrow = hbuf + (size_t)(off + row0 + lr) * II;
#pragma unroll
                for (int n = 0; n < 2; n++) {
                    const int col = n0 + wn * 32 + n * 16 + l15;   // C col = lane&15
                    float g = accg[m][n][r], u = accu[m][n][r];
                    float h = g / (1.f + __expf(-g)) * u;
                    hrow[col] = __float2bfloat16(h);
                }
            }
        }
    }
}

// ---------------- GEMM2: out += (h @ w2[e]^T) * route_w, tile 128x128, BK=32 ----------------
__global__ __launch_bounds__(256, 2) void gemm2_scatter(
    const __hip_bfloat16* __restrict__ hbuf, const float* __restrict__ w2,
    const int* __restrict__ list_tok, const float* __restrict__ list_w,
    const int* __restrict__ counts, float* __restrict__ out) {
    const int e = blockIdx.y >> 4;
    const int mt = blockIdx.y & 15;
    const int cnt = counts[e];
    const int row0 = mt * 128;
    if (row0 >= cnt) return;
    int off = 0;
#pragma unroll
    for (int i = 0; i < NE; i++) if (i < e) off += counts[i];
    const int valid = min(128, cnt - row0);
    const int n0 = blockIdx.x * 128;
    const int tid = threadIdx.x;

    __shared__ uint4 As[2][512];
    __shared__ uint4 Bs[2][512];

    const int ar0 = tid >> 2, au = tid & 3;
    const int ar1 = ar0 + 64;
    const size_t hr0 = (size_t)(off + row0 + min(ar0, valid - 1)) * II + au * 8;
    const size_t hr1 = (size_t)(off + row0 + min(ar1, valid - 1)) * II + au * 8;
    const float* bS0 = w2 + (size_t)e * HH * II + (size_t)(n0 + ar0) * II + au * 8;
    const float* bS1 = bS0 + (size_t)64 * II;
    const int awi0 = ar0 * 4 + (au ^ ((ar0 >> 1) & 3));
    const int awi1 = ar1 * 4 + (au ^ ((ar1 >> 1) & 3));

    struct R2 { uint4 a0, a1; float4 b0, b1, b2, b3; };
    R2 ra, rb;
    auto LD = [&](R2& r, int kt) {
        const int k = kt * 32;
        r.b0 = *(const float4*)(bS0 + k); r.b1 = *(const float4*)(bS0 + k + 4);
        r.b2 = *(const float4*)(bS1 + k); r.b3 = *(const float4*)(bS1 + k + 4);
        r.a0 = *(const uint4*)(hbuf + hr0 + k);
        r.a1 = *(const uint4*)(hbuf + hr1 + k);
    };
    auto ST = [&](const R2& r, int b) {
        As[b][awi0] = r.a0;
        As[b][awi1] = r.a1;
        Bs[b][awi0] = pk8(r.b0, r.b1);
        Bs[b][awi1] = pk8(r.b2, r.b3);
    };

    // wave tile 64x64
    const int lane = tid & 63;
    const int wv = tid >> 6;
    const int wm = wv >> 1, wn = wv & 1;
    const int l15 = lane & 15, ks = lane >> 4;
    int aidx[4], bidx[4];
#pragma unroll
    for (int m = 0; m < 4; m++) { int r = wm * 64 + m * 16 + l15; aidx[m] = r * 4 + (ks ^ ((r >> 1) & 3)); }
#pragma unroll
    for (int n = 0; n < 4; n++) { int c = wn * 64 + n * 16 + l15; bidx[n] = c * 4 + (ks ^ ((c >> 1) & 3)); }

    f32x4 acc[4][4];
#pragma unroll
    for (int m = 0; m < 4; m++)
#pragma unroll
        for (int n = 0; n < 4; n++) acc[m][n] = 0;

    auto RD = [&](int b, bf16x8* af, bf16x8* bf) {
#pragma unroll
        for (int m = 0; m < 4; m++) { uint4 t = As[b][aidx[m]]; af[m] = __builtin_bit_cast(bf16x8, t); }
#pragma unroll
        for (int n = 0; n < 4; n++) { uint4 t = Bs[b][bidx[n]]; bf[n] = __builtin_bit_cast(bf16x8, t); }
    };
    auto MM = [&](bf16x8* af, bf16x8* bf) {
#pragma unroll
        for (int m = 0; m < 4; m++)
#pragma unroll
            for (int n = 0; n < 4; n++)
                acc[m][n] = __builtin_amdgcn_mfma_f32_16x16x32_bf16(af[m], bf[n], acc[m][n], 0, 0, 0);
    };

    const int KT = II / 32;  // 176 (even)
    LD(ra, 0); LD(rb, 1);
    ST(ra, 0);
    FENCE();
    for (int kt = 0; kt < KT; kt += 2) {
        {
            bf16x8 af[4], bf[4];
            RD(0, af, bf);
            if (kt + 2 < KT) LD(ra, kt + 2);
            ST(rb, 1);
            FENCE();
            MM(af, bf);
        }
        {
            bf16x8 af[4], bf[4];
            RD(1, af, bf);
            if (kt + 3 < KT) LD(rb, kt + 3);
            if (kt + 2 < KT) ST(ra, 0);
            FENCE();
            MM(af, bf);
        }
    }

    // epilogue: scale by routing weight, scatter-add to out
#pragma unroll
    for (int m = 0; m < 4; m++) {
#pragma unroll
        for (int r = 0; r < 4; r++) {
            const int lr = wm * 64 + m * 16 + ks * 4 + r;
            if (lr < valid) {
                const int tok = list_tok[e * TT + row0 + lr];
                const float wt = list_w[e * TT + row0 + lr];
                float* orow = out + (size_t)tok * HH;
#pragma unroll
                for (int n = 0; n < 4; n++) {
                    const int col = n0 + wn * 64 + n * 16 + l15;
                    atomicAdd(orow + col, acc[m][n][r] * wt);
                }
            }
        }
    }
}

extern "C" void kernel_launch(void* const* d_in, const int* in_sizes, int n_in,
                              void* d_out, int out_size, void* d_ws, size_t ws_size,
                              hipStream_t stream) {
    const float* x      = (const float*)d_in[0];
    const float* gating = (const float*)d_in[1];
    const float* w1     = (const float*)d_in[2];
    const float* w2     = (const float*)d_in[3];
    float* out = (float*)d_out;
    char* ws = (char*)d_ws;

    int*   list_tok = (int*)(ws + 0);              // 64 KB
    float* list_w   = (float*)(ws + (64 << 10));   // 64 KB
    int*   counts   = (int*)(ws + (128 << 10));    // 32 B
    int*   tk_idx   = (int*)(ws + (132 << 10));    // 16 KB
    float* tk_w     = (float*)(ws + (148 << 10));  // 16 KB
    __hip_bfloat16* hbuf = (__hip_bfloat16*)(ws + (1 << 20));  // 4096 x 5632 bf16 = 46.1 MB

    // xb (bf16 x, 8.4 MB) lives in d_out until gemm1 is done; memset before gemm2.
    __hip_bfloat16* xb = (__hip_bfloat16*)d_out;

    route_topk<<<TT / 256, 256, 0, stream>>>(gating, tk_idx, tk_w);
    build_lists<<<NE, 256, 0, stream>>>(tk_idx, tk_w, list_tok, list_w, counts);
    cvt_x<<<TT * HH / (256 * 8), 256, 0, stream>>>(x, xb);
    gemm1_swiglu<<<dim3(II / 64, NE * 16), 256, 0, stream>>>(xb, w1, list_tok, counts, hbuf);
    (void)hipMemsetAsync(d_out, 0, (size_t)TT * HH * sizeof(float), stream);
    gemm2_scatter<<<dim3(HH / 128, NE * 16), 256, 0, stream>>>(hbuf, w2, list_tok, list_w, counts, out);
}

// Round 6
// 790.561 us; speedup vs baseline: 4.6620x; 1.9377x over previous
//
#include <hip/hip_runtime.h>
#include <hip/hip_bf16.h>

// MoE: T=2048, H=2048, I=5632, E=8, top-2 renormalized.
// route -> per-expert lists -> cvt x to bf16 (scratch = d_out) -> grouped GEMM1
// (x@w1^T fused SwiGLU -> bf16 h in ws) -> memset out -> grouped GEMM2 (h@w2^T * w, atomicAdd).
// GEMMs: global_load_lds direct staging, 3 LDS buffers, counted vmcnt(12) pipeline
// (tiles kt+1..kt+3 in flight; never drain vmcnt to 0 in the main loop).
// LDS is linear (load_lds writes base+lane*16); XOR swizzle is applied to the
// per-lane GLOBAL source address and to the ds_read index (rule: both-sides-or-neither).
// NOTE (R4/R5 lesson): register-staged pipelines spill here (WRITE_SIZE 45MB->900MB+).

#define TT 2048
#define HH 2048
#define II 5632
#define NE 8

using f32x4  = __attribute__((ext_vector_type(4))) float;
using bf16x8 = __attribute__((ext_vector_type(8))) short;

__device__ __forceinline__ uint32_t bfbits(float f) {
    __hip_bfloat16 h = __float2bfloat16(f);
    unsigned short u;
    __builtin_memcpy(&u, &h, 2);
    return (uint32_t)u;
}
__device__ __forceinline__ uint32_t pk2(float a, float b) {
    return bfbits(a) | (bfbits(b) << 16);
}
__device__ __forceinline__ uint4 pk8(const float4& a, const float4& b) {
    uint4 r;
    r.x = pk2(a.x, a.y); r.y = pk2(a.z, a.w);
    r.z = pk2(b.x, b.y); r.w = pk2(b.z, b.w);
    return r;
}

__device__ __forceinline__ void gl16(const void* g, void* l) {
    __builtin_amdgcn_global_load_lds(
        (const __attribute__((address_space(1))) unsigned int*)g,
        (__attribute__((address_space(3))) unsigned int*)l, 16, 0, 0);
}

#define VMW(n) do { asm volatile("s_waitcnt vmcnt(" #n ")" ::: "memory"); \
                    __builtin_amdgcn_sched_barrier(0); } while (0)
#define LGKM0() do { asm volatile("s_waitcnt lgkmcnt(0)" ::: "memory"); \
                     __builtin_amdgcn_sched_barrier(0); } while (0)
#define BARR() do { __builtin_amdgcn_s_barrier(); \
                    __builtin_amdgcn_sched_barrier(0); } while (0)

// ---------------- x -> bf16 ----------------
__global__ void cvt_x(const float* __restrict__ x, __hip_bfloat16* __restrict__ xb) {
    const int i = (blockIdx.x * 256 + threadIdx.x) * 8;
    float4 a = *(const float4*)(x + i);
    float4 b = *(const float4*)(x + i + 4);
    *(uint4*)(xb + i) = pk8(a, b);
}

// ---------------- routing ----------------
__global__ void route_topk(const float* __restrict__ gating,
                           int* __restrict__ tk_idx, float* __restrict__ tk_w) {
    int t = blockIdx.x * 256 + threadIdx.x;
    if (t >= TT) return;
    float g[NE];
#pragma unroll
    for (int e = 0; e < NE; e++) g[e] = gating[t * NE + e];
    int i0 = 0; float b0 = g[0];
#pragma unroll
    for (int e = 1; e < NE; e++) if (g[e] > b0) { b0 = g[e]; i0 = e; }
    int i1 = (i0 == 0) ? 1 : 0; float b1 = g[i1];
#pragma unroll
    for (int e = 0; e < NE; e++) if (e != i0 && g[e] > b1) { b1 = g[e]; i1 = e; }
    float ex = expf(b1 - b0);
    float w0 = 1.f / (1.f + ex);
    float w1 = ex / (1.f + ex);
    tk_idx[2 * t] = i0; tk_idx[2 * t + 1] = i1;
    tk_w[2 * t] = w0;  tk_w[2 * t + 1] = w1;
}

__global__ void build_lists(const int* __restrict__ tk_idx, const float* __restrict__ tk_w,
                            int* __restrict__ list_tok, float* __restrict__ list_w,
                            int* __restrict__ counts) {
    const int e = blockIdx.x;
    const int tid = threadIdx.x;
    int flag[8]; float wt[8];
    int cnt = 0;
#pragma unroll
    for (int j = 0; j < 8; j++) {
        int t = tid * 8 + j;
        int f = -1;
        if (tk_idx[2 * t] == e) f = 0;
        else if (tk_idx[2 * t + 1] == e) f = 1;
        flag[j] = f;
        wt[j] = (f >= 0) ? tk_w[2 * t + f] : 0.f;
        cnt += (f >= 0) ? 1 : 0;
    }
    __shared__ int s[256];
    s[tid] = cnt;
    __syncthreads();
    for (int d = 1; d < 256; d <<= 1) {
        int v = (tid >= d) ? s[tid - d] : 0;
        __syncthreads();
        s[tid] += v;
        __syncthreads();
    }
    int pos = s[tid] - cnt;
#pragma unroll
    for (int j = 0; j < 8; j++) {
        if (flag[j] >= 0) {
            list_tok[e * TT + pos] = tid * 8 + j;
            list_w[e * TT + pos] = wt[j];
            pos++;
        }
    }
    if (tid == 255) counts[e] = s[255];
}

// ---------------- GEMM1: h = SwiGLU(Xe @ w1[e]^T), tile 128(M) x 64(N of I), BK=32 ----------------
// LDS/buf: A bf16 [128 rows][4 slot16] = 8KB; Bg f32 [64][8 slot16] = 8KB; Bu same. x3 bufs = 72KB.
__global__ __launch_bounds__(256, 2) void gemm1_swiglu(
    const __hip_bfloat16* __restrict__ xb, const float* __restrict__ w1,
    const int* __restrict__ list_tok, const int* __restrict__ counts,
    __hip_bfloat16* __restrict__ hbuf) {
    const int e = blockIdx.y >> 4;
    const int mt = blockIdx.y & 15;
    const int cnt = counts[e];
    const int row0 = mt * 128;
    if (row0 >= cnt) return;
    int off = 0;
#pragma unroll
    for (int i = 0; i < NE; i++) if (i < e) off += counts[i];
    const int valid = min(128, cnt - row0);
    const int n0 = blockIdx.x * 64;
    const int tid = threadIdx.x;
    const int w = tid >> 6, l = tid & 63;

    __shared__ uint4  As[3 * 512];
    __shared__ float4 Gs[3 * 512];
    __shared__ float4 Us[3 * 512];

    // staging sources (per-lane, pre-swizzled)
    // A call c: row = c*64 + w*16 + (l>>2), pslot = l&3, lslot = pslot ^ ((row>>1)&3)
    const char* aSrc0; const char* aSrc1;
    {
        int r0 = w * 16 + (l >> 2);
        int r1 = 64 + r0;
        int t0 = list_tok[e * TT + row0 + min(r0, valid - 1)];
        int t1 = list_tok[e * TT + row0 + min(r1, valid - 1)];
        int s0 = (l & 3) ^ ((r0 >> 1) & 3);
        int s1 = (l & 3) ^ ((r1 >> 1) & 3);
        aSrc0 = (const char*)(xb + (size_t)t0 * HH + s0 * 8);
        aSrc1 = (const char*)(xb + (size_t)t1 * HH + s1 * 8);
    }
    // B call c: row = c*32 + w*8 + (l>>3), pslot = l&7, lslot = pslot ^ (row&7)
    const char *gSrc0, *gSrc1, *uSrc0, *uSrc1;
    {
        const float* base = w1 + (size_t)e * (2 * II) * HH;
        int r0 = w * 8 + (l >> 3);
        int r1 = 32 + r0;
        int s0 = (l & 7) ^ (r0 & 7);
        int s1 = (l & 7) ^ (r1 & 7);
        gSrc0 = (const char*)(base + (size_t)(n0 + r0) * HH + s0 * 4);
        gSrc1 = (const char*)(base + (size_t)(n0 + r1) * HH + s1 * 4);
        uSrc0 = (const char*)(base + (size_t)(II + n0 + r0) * HH + s0 * 4);
        uSrc1 = (const char*)(base + (size_t)(II + n0 + r1) * HH + s1 * 4);
    }

    auto STAGE = [&](int kt, int buf) {
        const size_t kA = (size_t)kt * 64;    // 32 bf16
        const size_t kB = (size_t)kt * 128;   // 32 f32
        char* ab = (char*)As + buf * 8192 + w * 1024;
        gl16(aSrc0 + kA, ab);
        gl16(aSrc1 + kA, ab + 4096);
        char* gb = (char*)Gs + buf * 8192 + w * 1024;
        gl16(gSrc0 + kB, gb);
        gl16(gSrc1 + kB, gb + 4096);
        char* ub = (char*)Us + buf * 8192 + w * 1024;
        gl16(uSrc0 + kB, ub);
        gl16(uSrc1 + kB, ub + 4096);
    };

    // fragment indices: wave grid 2x2, wave tile 64(M) x 32(N)
    const int wm = w >> 1, wn = w & 1;
    const int l15 = l & 15, ks = l >> 4;
    int aidx[4];
#pragma unroll
    for (int m = 0; m < 4; m++) { int r = wm * 64 + m * 16 + l15; aidx[m] = r * 4 + (ks ^ ((r >> 1) & 3)); }
    int bbase[2], bo0[2], bo1[2];
#pragma unroll
    for (int n = 0; n < 2; n++) {
        int c_ = wn * 32 + n * 16 + l15;
        bbase[n] = c_ * 8;
        bo0[n] = (2 * ks) ^ (c_ & 7);
        bo1[n] = (2 * ks + 1) ^ (c_ & 7);
    }

    f32x4 accg[4][2], accu[4][2];
#pragma unroll
    for (int m = 0; m < 4; m++)
#pragma unroll
        for (int n = 0; n < 2; n++) { accg[m][n] = 0; accu[m][n] = 0; }

    const int KT = HH / 32;  // 64
    STAGE(0, 0); STAGE(1, 1); STAGE(2, 2);
    VMW(12);
    BARR();

    int b = 0;
    for (int kt = 0; kt < KT; ++kt) {
        bf16x8 af[4];
        float4 glo[2], ghi[2], ulo[2], uhi[2];
        {
            const uint4*  Ab = As + b * 512;
            const float4* Gb = Gs + b * 512;
            const float4* Ub = Us + b * 512;
#pragma unroll
            for (int m = 0; m < 4; m++) { uint4 t = Ab[aidx[m]]; af[m] = __builtin_bit_cast(bf16x8, t); }
#pragma unroll
            for (int n = 0; n < 2; n++) {
                glo[n] = Gb[bbase[n] + bo0[n]]; ghi[n] = Gb[bbase[n] + bo1[n]];
                ulo[n] = Ub[bbase[n] + bo0[n]]; uhi[n] = Ub[bbase[n] + bo1[n]];
            }
        }
        if (kt + 3 < KT) {
            LGKM0();            // my reads of buf b landed in regs
            BARR();             // everyone's reads of buf b done -> safe to overwrite
            STAGE(kt + 3, b);
        }
        bf16x8 gf[2], uf[2];
#pragma unroll
        for (int n = 0; n < 2; n++) {
            uint4 tg = pk8(glo[n], ghi[n]); gf[n] = __builtin_bit_cast(bf16x8, tg);
            uint4 tu = pk8(ulo[n], uhi[n]); uf[n] = __builtin_bit_cast(bf16x8, tu);
        }
#pragma unroll
        for (int m = 0; m < 4; m++)
#pragma unroll
            for (int n = 0; n < 2; n++) {
                accg[m][n] = __builtin_amdgcn_mfma_f32_16x16x32_bf16(af[m], gf[n], accg[m][n], 0, 0, 0);
                accu[m][n] = __builtin_amdgcn_mfma_f32_16x16x32_bf16(af[m], uf[n], accu[m][n], 0, 0, 0);
            }
        if (kt + 3 < KT)      VMW(12);   // tile kt+1 (my 6 oldest) landed
        else if (kt + 2 < KT) VMW(6);
        else if (kt + 1 < KT) VMW(0);
        if (kt + 1 < KT) BARR();
        b = (b == 2) ? 0 : b + 1;
    }

    // epilogue: h = silu(g)*u -> bf16
#pragma unroll
    for (int m = 0; m < 4; m++) {
#pragma unroll
        for (int r = 0; r < 4; r++) {
            const int lr = wm * 64 + m * 16 + ks * 4 + r;   // C row = (lane>>4)*4 + reg
            if (lr < valid) {
                __hip_bfloat16* hrow = hbuf + (size_t)(off + row0 + lr) * II;
#pragma unroll
                for (int n = 0; n < 2; n++) {
                    const int col = n0 + wn * 32 + n * 16 + l15;   // C col = lane&15
                    float g = accg[m][n][r], u = accu[m][n][r];
                    float h = g / (1.f + __expf(-g)) * u;
                    hrow[col] = __float2bfloat16(h);
                }
            }
        }
    }
}

// ---------------- GEMM2: out += (h @ w2[e]^T) * route_w, tile 128x128, BK=32 ----------------
// LDS/buf: A bf16 [128][4 slot16] = 8KB; B f32 [128][8 slot16] = 16KB. x3 = 72KB.
__global__ __launch_bounds__(256, 2) void gemm2_scatter(
    const __hip_bfloat16* __restrict__ hbuf, const float* __restrict__ w2,
    const int* __restrict__ list_tok, const float* __restrict__ list_w,
    const int* __restrict__ counts, float* __restrict__ out) {
    const int e = blockIdx.y >> 4;
    const int mt = blockIdx.y & 15;
    const int cnt = counts[e];
    const int row0 = mt * 128;
    if (row0 >= cnt) return;
    int off = 0;
#pragma unroll
    for (int i = 0; i < NE; i++) if (i < e) off += counts[i];
    const int valid = min(128, cnt - row0);
    const int n0 = blockIdx.x * 128;
    const int tid = threadIdx.x;
    const int w = tid >> 6, l = tid & 63;

    __shared__ uint4  As[3 * 512];
    __shared__ float4 Bs[3 * 1024];

    const char* aSrc0; const char* aSrc1;
    {
        int r0 = w * 16 + (l >> 2);
        int r1 = 64 + r0;
        int s0 = (l & 3) ^ ((r0 >> 1) & 3);
        int s1 = (l & 3) ^ ((r1 >> 1) & 3);
        size_t h0 = (size_t)(off + row0 + min(r0, valid - 1)) * II;
        size_t h1 = (size_t)(off + row0 + min(r1, valid - 1)) * II;
        aSrc0 = (const char*)(hbuf + h0 + s0 * 8);
        aSrc1 = (const char*)(hbuf + h1 + s1 * 8);
    }
    const char* bSrc[4];
    {
        const float* base = w2 + (size_t)e * HH * II;
#pragma unroll
        for (int c = 0; c < 4; c++) {
            int r = c * 32 + w * 8 + (l >> 3);
            int s = (l & 7) ^ (r & 7);
            bSrc[c] = (const char*)(base + (size_t)(n0 + r) * II + s * 4);
        }
    }

    auto STAGE = [&](int kt, int buf) {
        const size_t kA = (size_t)kt * 64;
        const size_t kB = (size_t)kt * 128;
        char* ab = (char*)As + buf * 8192 + w * 1024;
        gl16(aSrc0 + kA, ab);
        gl16(aSrc1 + kA, ab + 4096);
        char* bb = (char*)Bs + buf * 16384 + w * 1024;
        gl16(bSrc[0] + kB, bb);
        gl16(bSrc[1] + kB, bb + 4096);
        gl16(bSrc[2] + kB, bb + 8192);
        gl16(bSrc[3] + kB, bb + 12288);
    };

    // wave tile 64x64 (wave grid 2x2)
    const int wm = w >> 1, wn = w & 1;
    const int l15 = l & 15, ks = l >> 4;
    int aidx[4];
#pragma unroll
    for (int m = 0; m < 4; m++) { int r = wm * 64 + m * 16 + l15; aidx[m] = r * 4 + (ks ^ ((r >> 1) & 3)); }
    int bbase[4], bo0[4], bo1[4];
#pragma unroll
    for (int n = 0; n < 4; n++) {
        int c_ = wn * 64 + n * 16 + l15;
        bbase[n] = c_ * 8;
        bo0[n] = (2 * ks) ^ (c_ & 7);
        bo1[n] = (2 * ks + 1) ^ (c_ & 7);
    }

    f32x4 acc[4][4];
#pragma unroll
    for (int m = 0; m < 4; m++)
#pragma unroll
        for (int n = 0; n < 4; n++) acc[m][n] = 0;

    const int KT = II / 32;  // 176
    STAGE(0, 0); STAGE(1, 1); STAGE(2, 2);
    VMW(12);
    BARR();

    int b = 0;
    for (int kt = 0; kt < KT; ++kt) {
        bf16x8 af[4];
        float4 blo[4], bhi[4];
        {
            const uint4*  Ab = As + b * 512;
            const float4* Bb = Bs + b * 1024;
#pragma unroll
            for (int m = 0; m < 4; m++) { uint4 t = Ab[aidx[m]]; af[m] = __builtin_bit_cast(bf16x8, t); }
#pragma unroll
            for (int n = 0; n < 4; n++) {
                blo[n] = Bb[bbase[n] + bo0[n]];
                bhi[n] = Bb[bbase[n] + bo1[n]];
            }
        }
        if (kt + 3 < KT) {
            LGKM0();
            BARR();
            STAGE(kt + 3, b);
        }
        bf16x8 bf[4];
#pragma unroll
        for (int n = 0; n < 4; n++) {
            uint4 t = pk8(blo[n], bhi[n]); bf[n] = __builtin_bit_cast(bf16x8, t);
        }
#pragma unroll
        for (int m = 0; m < 4; m++)
#pragma unroll
            for (int n = 0; n < 4; n++)
                acc[m][n] = __builtin_amdgcn_mfma_f32_16x16x32_bf16(af[m], bf[n], acc[m][n], 0, 0, 0);
        if (kt + 3 < KT)      VMW(12);
        else if (kt + 2 < KT) VMW(6);
        else if (kt + 1 < KT) VMW(0);
        if (kt + 1 < KT) BARR();
        b = (b == 2) ? 0 : b + 1;
    }

    // epilogue: scale by routing weight, scatter-add to out
#pragma unroll
    for (int m = 0; m < 4; m++) {
#pragma unroll
        for (int r = 0; r < 4; r++) {
            const int lr = wm * 64 + m * 16 + ks * 4 + r;
            if (lr < valid) {
                const int tok = list_tok[e * TT + row0 + lr];
                const float wt = list_w[e * TT + row0 + lr];
                float* orow = out + (size_t)tok * HH;
#pragma unroll
                for (int n = 0; n < 4; n++) {
                    const int col = n0 + wn * 64 + n * 16 + l15;
                    atomicAdd(orow + col, acc[m][n][r] * wt);
                }
            }
        }
    }
}

extern "C" void kernel_launch(void* const* d_in, const int* in_sizes, int n_in,
                              void* d_out, int out_size, void* d_ws, size_t ws_size,
                              hipStream_t stream) {
    const float* x      = (const float*)d_in[0];
    const float* gating = (const float*)d_in[1];
    const float* w1     = (const float*)d_in[2];
    const float* w2     = (const float*)d_in[3];
    float* out = (float*)d_out;
    char* ws = (char*)d_ws;

    int*   list_tok = (int*)(ws + 0);              // 64 KB
    float* list_w   = (float*)(ws + (64 << 10));   // 64 KB
    int*   counts   = (int*)(ws + (128 << 10));    // 32 B
    int*   tk_idx   = (int*)(ws + (132 << 10));    // 16 KB
    float* tk_w     = (float*)(ws + (148 << 10));  // 16 KB
    __hip_bfloat16* hbuf = (__hip_bfloat16*)(ws + (1 << 20));  // 4096 x 5632 bf16 = 46.1 MB

    // xb (bf16 x, 8.4 MB) lives in d_out until gemm1 is done; memset before gemm2.
    __hip_bfloat16* xb = (__hip_bfloat16*)d_out;

    route_topk<<<TT / 256, 256, 0, stream>>>(gating, tk_idx, tk_w);
    build_lists<<<NE, 256, 0, stream>>>(tk_idx, tk_w, list_tok, list_w, counts);
    cvt_x<<<TT * HH / (256 * 8), 256, 0, stream>>>(x, xb);
    gemm1_swiglu<<<dim3(II / 64, NE * 16), 256, 0, stream>>>(xb, w1, list_tok, counts, hbuf);
    (void)hipMemsetAsync(d_out, 0, (size_t)TT * HH * sizeof(float), stream);
    gemm2_scatter<<<dim3(HH / 128, NE * 16), 256, 0, stream>>>(hbuf, w2, list_tok, list_w, counts, out);
}